// Round 12
// baseline (403.335 us; speedup 1.0000x reference)
//
#include <hip/hip_runtime.h>
#include <stdint.h>
#include <stddef.h>

#define HIDDEN 2048
#define INTER  5632
#define TOKENS 4096   // B*S = 2*2048
#define BKD    64     // f16 K-tile (down GEMM): 128B rows, 88 iters
#define BKI    128    // i8 K-tile (gateup GEMM): 128B rows, 16 iters
#define NT_GU  (HIDDEN / BKI)   // 16
#define NT_DN  (INTER / BKD)    // 88

typedef __attribute__((ext_vector_type(8)))  _Float16 f16x8;
typedef __attribute__((ext_vector_type(4)))  _Float16 f16x4;
typedef __attribute__((ext_vector_type(4)))  float    f32x4;
typedef __attribute__((ext_vector_type(4)))  int      i32x4;

// 128B-row LDS swizzle, period-8 row rotation: global segment q of row r lives
// at slot r*8 + ((q + r) & 7).  With the 16x16 fragment read pattern (16
// consecutive rows per 16-lane group, q per group) this is conflict-free
// [HW-verified: SQ_LDS_BANK_CONFLICT = 0 in R0/R3/R4/R7/R10].  The 32x32
// pattern conflicts (R11, +4cyc/read) -- do not use 32x32 shapes with swz8.
__device__ __forceinline__ int swz8(int row, int q) {
    return row * 8 + ((q + row) & 7);
}

#define GLDS16(g, l) __builtin_amdgcn_global_load_lds( \
    (__attribute__((address_space(1))) void*)(g), \
    (__attribute__((address_space(3))) void*)(l), 16, 0, 0)

__device__ __forceinline__ int pack4i8(float4 f) {
    return ((int)(signed char)(int)f.x & 255)
         | (((int)(signed char)(int)f.y & 255) << 8)
         | (((int)(signed char)(int)f.z & 255) << 16)
         | (((int)(signed char)(int)f.w) << 24);
}

// ---------------------------------------------------------------------------
// fused prepass (R7 version; measured ~30-33us ~= its 35.6us BW roofline via
// the R9 3x-launch experiment; no further headroom).
// ---------------------------------------------------------------------------
__global__ __launch_bounds__(256)
void prepass(const float* __restrict__ x,
             const float4* __restrict__ gw, const float4* __restrict__ uw,
             const float4* __restrict__ dw,
             int8_t* __restrict__ xq, float* __restrict__ xs,
             int* __restrict__ go, int* __restrict__ uo,
             _Float16* __restrict__ dno) {
    const int tid = threadIdx.x;
    if (blockIdx.x < 1024) {
        const int wave = tid >> 6;
        const int lane = tid & 63;
        const int t    = blockIdx.x * 4 + wave;
        const float4* row = (const float4*)(x + (size_t)t * HIDDEN); // 512 f4
        float4 v[8];
        #pragma unroll
        for (int j = 0; j < 8; ++j) v[j] = row[lane + 64 * j];
        float m = 0.0f;
        #pragma unroll
        for (int j = 0; j < 8; ++j) {
            m = fmaxf(m, fmaxf(fmaxf(fabsf(v[j].x), fabsf(v[j].y)),
                               fmaxf(fabsf(v[j].z), fabsf(v[j].w))));
        }
        #pragma unroll
        for (int off = 32; off; off >>= 1)
            m = fmaxf(m, __shfl_xor(m, off, 64));
        m = fmaxf(m, 1e-20f);
        if (lane == 0) xs[t] = m * (1.0f / 127.0f);
        const float inv = 127.0f / m;
        int* oq = (int*)(xq + (size_t)t * HIDDEN);
        #pragma unroll
        for (int j = 0; j < 8; ++j) {
            float4 f = v[j];
            f.x *= inv; f.y *= inv; f.z *= inv; f.w *= inv;
            float4 r;
            r.x = rintf(f.x); r.y = rintf(f.y); r.z = rintf(f.z); r.w = rintf(f.w);
            oq[lane + 64 * j] = pack4i8(r);
        }
        return;
    }
    const int NA = INTER * HIDDEN / 16;   // 720896
    const int NC = INTER * HIDDEN / 8;    // 1441792
    const int stride = 2048 * 256;
    for (int u = (blockIdx.x - 1024) * 256 + tid; u < 2 * NA + NC; u += stride) {
        if (u < 2 * NA) {
            const bool is_g = u < NA;
            const int j = is_g ? u : u - NA;
            const float4* src = (is_g ? gw : uw) + (size_t)j * 4;
            float4 f0 = src[0], f1 = src[1], f2 = src[2], f3 = src[3];
            int4 p;
            p.x = pack4i8(f0); p.y = pack4i8(f1);
            p.z = pack4i8(f2); p.w = pack4i8(f3);
            ((int4*)(is_g ? go : uo))[j] = p;
        } else {
            const int j = u - 2 * NA;
            const float4* src = dw + (size_t)j * 2;
            float4 a = src[0], b = src[1];
            f16x8 o;
            o[0] = (_Float16)a.x; o[1] = (_Float16)a.y;
            o[2] = (_Float16)a.z; o[3] = (_Float16)a.w;
            o[4] = (_Float16)b.x; o[5] = (_Float16)b.y;
            o[6] = (_Float16)b.z; o[7] = (_Float16)b.w;
            *(f16x8*)(dno + (size_t)j * 8) = o;
        }
    }
}

// ---------------------------------------------------------------------------
// GEMM1 fused (i8): H = silu(G*xs*gs) * (U*xs*us)  (fp16 out)
// NEW (R12): 256x128 tile, 512 thr (8 waves 4Mx2N, wave tile 64x64 verbatim
// from R10), BKI=128, DOUBLE-buffered LDS 2x64KB = 128KB -> exactly 1 block/
// CU with 2 waves/SIMD.  Single-barrier iteration:
//   reads(all frags of buf[cur]) ; STAGE(t+1 -> buf[cur^1]) ; MFMA ; sync
// Removes R10's sync#1 (reads<->stage serialization).  Reads precede the
// stage writes in program order (no alias stall -- R3's failure mode dodged);
// cross-iter hazards are covered by the single end barrier (drains vmcnt
// after ~2600cyc of MFMA -> drain ~free).  16x16 MFMA + swz8 (0 conflicts).
// Grid 704 = 16m x 44n, XCD-chunked (704 = 8*88).
// ---------------------------------------------------------------------------
__global__ __launch_bounds__(512, 2)
void gemm_gateup(const int8_t* __restrict__ Xq,
                 const int8_t* __restrict__ Wg,
                 const int8_t* __restrict__ Wu,
                 const float* __restrict__ xs,
                 const float* __restrict__ gs,
                 const float* __restrict__ us,
                 _Float16* __restrict__ Hm) {
    __shared__ int8_t As [2][256 * BKI];   // 2 x 32KB
    __shared__ int8_t Bgs[2][128 * BKI];   // 2 x 16KB
    __shared__ int8_t Bus[2][128 * BKI];   // 2 x 16KB

    const int pid = (blockIdx.x % 8) * 88 + blockIdx.x / 8;
    const int bm  = (pid & 15) * 256;      // 16 m-tiles (m-fast band)
    const int bn  = (pid >> 4) * 128;      // 44 n-tiles

    const int tid  = threadIdx.x;          // 0..511
    const int lane = tid & 63;
    const int wave = tid >> 6;             // 0..7
    const int wm   = (wave >> 1) * 64;     // 4 M-waves
    const int wn   = (wave & 1) * 64;      // 2 N-waves
    const int l15  = lane & 15;
    const int lq   = lane >> 4;

    // staging slots (16B): A = 2048 (4 rounds of 512 thr), B = 1024 (2 rounds)
    int rowS[4], segS[4];
    #pragma unroll
    for (int j = 0; j < 4; ++j) {
        const int f = tid + 512 * j;
        rowS[j] = f >> 3;
        segS[j] = (((f & 7) - (f >> 3)) & 7) * 16;
    }

    #define STG_GU(b, k0) do { \
        _Pragma("unroll") \
        for (int j = 0; j < 4; ++j) { \
            const int f_ = tid + 512 * j; \
            GLDS16(Xq + (size_t)(bm + rowS[j]) * HIDDEN + (k0) + segS[j], \
                   &As[b][f_ * 16]); \
        } \
        _Pragma("unroll") \
        for (int j = 0; j < 2; ++j) { \
            const int f_ = tid + 512 * j; \
            const size_t o_ = (size_t)(bn + rowS[j]) * HIDDEN + (k0) + segS[j]; \
            GLDS16(Wg + o_, &Bgs[b][f_ * 16]); \
            GLDS16(Wu + o_, &Bus[b][f_ * 16]); \
        } \
    } while (0)

    i32x4 accg[4][4] = {};
    i32x4 accu[4][4] = {};

    STG_GU(0, 0);
    __syncthreads();

    int cur = 0;
    for (int t = 0; t < NT_GU; ++t) {
        const int8_t* A_ = As [cur];
        const int8_t* G_ = Bgs[cur];
        const int8_t* U_ = Bus[cur];

        // read ALL fragments of tile t (before any stage-issue)
        i32x4 a[2][4], bg[2][4], bu[2][4];
        #pragma unroll
        for (int ks = 0; ks < 2; ++ks) {
            const int q = ks * 4 + lq;
            #pragma unroll
            for (int im = 0; im < 4; ++im)
                a[ks][im] = *(const i32x4*)&A_[swz8(wm + im * 16 + l15, q) * 16];
            #pragma unroll
            for (int jn = 0; jn < 4; ++jn) {
                bg[ks][jn] = *(const i32x4*)&G_[swz8(wn + jn * 16 + l15, q) * 16];
                bu[ks][jn] = *(const i32x4*)&U_[swz8(wn + jn * 16 + l15, q) * 16];
            }
        }
        if (t + 1 < NT_GU) STG_GU(cur ^ 1, (t + 1) * BKI);   // other buffer
        #pragma unroll
        for (int ks = 0; ks < 2; ++ks)
            #pragma unroll
            for (int jn = 0; jn < 4; ++jn)
                #pragma unroll
                for (int im = 0; im < 4; ++im) {
                    accg[im][jn] = __builtin_amdgcn_mfma_i32_16x16x64_i8(a[ks][im], bg[ks][jn], accg[im][jn], 0, 0, 0);
                    accu[im][jn] = __builtin_amdgcn_mfma_i32_16x16x64_i8(a[ks][im], bu[ks][jn], accu[im][jn], 0, 0, 0);
                }
        __syncthreads();   // single barrier: publishes buf[cur^1], frees buf[cur]
        cur ^= 1;
    }
    #undef STG_GU

    #pragma unroll
    for (int jn = 0; jn < 4; ++jn) {
        const int col = bn + wn + jn * 16 + l15;
        const float sg = gs[col];
        const float su = us[col];
        #pragma unroll
        for (int im = 0; im < 4; ++im) {
            const int rbase = bm + wm + im * 16 + lq * 4;
            #pragma unroll
            for (int r = 0; r < 4; ++r) {
                const int row = rbase + r;
                const float st = xs[row];
                float g = (float)accg[im][jn][r] * st * sg;
                float u = (float)accu[im][jn][r] * st * su;
                float h = (g / (1.0f + __expf(-g))) * u;
                Hm[(size_t)row * INTER + col] = (_Float16)h;
            }
        }
    }
}

// ---------------------------------------------------------------------------
// GEMM2 (fp16): out = (H @ Wd^T) * down_s  (fp32 out)
// NEW (R12): 256x128 tile, 512 thr (8 waves 4Mx2N, wave tile 64x64), BKD=64,
// DOUBLE-buffered LDS 2x48KB = 96KB -> 1 block/CU, 2 waves/SIMD.  Same
// single-barrier read-first/stage-other-buffer schedule as gateup.
// Grid 256 = 16m x 16n = exactly 1 block/CU, no tail; XCD-chunked.
// ---------------------------------------------------------------------------
__global__ __launch_bounds__(512, 2)
void gemm_down(const _Float16* __restrict__ Hm,
               const _Float16* __restrict__ Wd,
               const float* __restrict__ dsc,
               float* __restrict__ out) {
    __shared__ _Float16 As[2][256 * BKD];   // 2 x 32KB
    __shared__ _Float16 Bs[2][128 * BKD];   // 2 x 16KB

    const int pid = (blockIdx.x % 8) * 32 + blockIdx.x / 8;
    const int bm  = (pid & 15) * 256;      // 16 m-tiles
    const int bn  = (pid >> 4) * 128;      // 16 n-tiles

    const int tid  = threadIdx.x;          // 0..511
    const int lane = tid & 63;
    const int wave = tid >> 6;             // 0..7
    const int wm   = (wave >> 1) * 64;
    const int wn   = (wave & 1) * 64;
    const int l15  = lane & 15;
    const int lq   = lane >> 4;

    // staging slots (16B = 8 f16): A = 2048 (4 rounds), B = 1024 (2 rounds)
    int rowS[4], segS[4];
    #pragma unroll
    for (int j = 0; j < 4; ++j) {
        const int f = tid + 512 * j;
        rowS[j] = f >> 3;
        segS[j] = (((f & 7) - (f >> 3)) & 7) * 8;   // f16 elements
    }

    #define STG_DN(b, k0) do { \
        _Pragma("unroll") \
        for (int j = 0; j < 4; ++j) { \
            const int f_ = tid + 512 * j; \
            GLDS16(Hm + (size_t)(bm + rowS[j]) * INTER + (k0) + segS[j], \
                   &As[b][f_ * 8]); \
        } \
        _Pragma("unroll") \
        for (int j = 0; j < 2; ++j) { \
            const int f_ = tid + 512 * j; \
            GLDS16(Wd + (size_t)(bn + rowS[j]) * INTER + (k0) + segS[j], \
                   &Bs[b][f_ * 8]); \
        } \
    } while (0)

    f32x4 acc[4][4] = {};

    STG_DN(0, 0);
    __syncthreads();

    int cur = 0;
    for (int t = 0; t < NT_DN; ++t) {
        const _Float16* A_ = As[cur];
        const _Float16* B_ = Bs[cur];

        f16x8 a[2][4], b[2][4];
        #pragma unroll
        for (int ks = 0; ks < 2; ++ks) {
            const int q = ks * 4 + lq;
            #pragma unroll
            for (int im = 0; im < 4; ++im)
                a[ks][im] = *(const f16x8*)&A_[swz8(wm + im * 16 + l15, q) * 8];
            #pragma unroll
            for (int jn = 0; jn < 4; ++jn)
                b[ks][jn] = *(const f16x8*)&B_[swz8(wn + jn * 16 + l15, q) * 8];
        }
        if (t + 1 < NT_DN) STG_DN(cur ^ 1, (t + 1) * BKD);   // other buffer
        #pragma unroll
        for (int ks = 0; ks < 2; ++ks)
            #pragma unroll
            for (int jn = 0; jn < 4; ++jn)
                #pragma unroll
                for (int im = 0; im < 4; ++im)
                    acc[im][jn] = __builtin_amdgcn_mfma_f32_16x16x32_f16(a[ks][im], b[ks][jn], acc[im][jn], 0, 0, 0);
        __syncthreads();
        cur ^= 1;
    }
    #undef STG_DN

    #pragma unroll
    for (int jn = 0; jn < 4; ++jn) {
        const int col = bn + wn + jn * 16 + l15;
        const float sd = dsc[col];
        #pragma unroll
        for (int im = 0; im < 4; ++im) {
            const int rbase = bm + wm + im * 16 + lq * 4;
            #pragma unroll
            for (int r = 0; r < 4; ++r)
                out[(size_t)(rbase + r) * HIDDEN + col] = acc[im][jn][r] * sd;
        }
    }
}

// ---------------------------------------------------------------------------
// launch
// ---------------------------------------------------------------------------
extern "C" void kernel_launch(void* const* d_in, const int* in_sizes, int n_in,
                              void* d_out, int out_size, void* d_ws, size_t ws_size,
                              hipStream_t stream) {
    const float* x   = (const float*)d_in[0];
    const float* gw  = (const float*)d_in[1];
    const float* uw  = (const float*)d_in[2];
    const float* dw  = (const float*)d_in[3];
    const float* gsc = (const float*)d_in[4];
    const float* usc = (const float*)d_in[5];
    const float* dsc = (const float*)d_in[6];
    float* out = (float*)d_out;

    // workspace layout:
    //   Xq  i8  @          0 :  8,388,608
    //   Wg8 i8  @  8,388,608 : 11,534,336
    //   Wu8 i8  @ 19,922,944 : 11,534,336
    //   Wdh f16 @ 31,457,280 : 23,068,672
    //   Hm  f16 @ 54,525,952 : 46,137,344
    //   xs  f32 @100,663,296 :     16,384
    char* ws = (char*)d_ws;
    int8_t*   Xq  = (int8_t*)(ws);
    int8_t*   Wg8 = (int8_t*)(ws + 8388608ull);
    int8_t*   Wu8 = (int8_t*)(ws + 19922944ull);
    _Float16* Wdh = (_Float16*)(ws + 31457280ull);
    _Float16* Hm  = (_Float16*)(ws + 54525952ull);
    float*    xs  = (float*)(ws + 100663296ull);

    prepass<<<1024 + 2048, 256, 0, stream>>>(
        x, (const float4*)gw, (const float4*)uw, (const float4*)dw,
        Xq, xs, (int*)Wg8, (int*)Wu8, Wdh);

    gemm_gateup<<<(INTER / 128) * (TOKENS / 256), 512, 0, stream>>>(
        Xq, Wg8, Wu8, xs, gsc, usc, Hm);
    gemm_down<<<(HIDDEN / 128) * (TOKENS / 256), 512, 0, stream>>>(
        Hm, Wdh, dsc, out);
}